// Round 7
// baseline (491.063 us; speedup 1.0000x reference)
//
#include <hip/hip_runtime.h>
#include <hip/hip_bf16.h>
#include <math.h>

#define N_NODES 50000
#define N_EDGES 800000
#define E_TOT   (N_EDGES + N_NODES)   // 850000 (with self-loops)
#define IN_CH 128
#define HID 32
#define HEADS 8
#define OUT_CH 64
#define NEG_SLOPE 0.2f
#define M_BLK 64
#define GBLK 782                      // ceil(50000/64)
#define ABLK 12500                    // 50000/4 nodes per 256-thread block

__device__ __forceinline__ float lrelu(float x) { return x > 0.f ? x : NEG_SLOPE * x; }

__device__ __forceinline__ unsigned short f2bf(float f) {
    unsigned int u = __float_as_uint(f);
    unsigned int r = (u + 0x7FFFu + ((u >> 16) & 1u)) >> 16;   // round-nearest-even
    return (unsigned short)r;
}
__device__ __forceinline__ float bf2f(unsigned short u) {
    return __uint_as_float(((unsigned int)u) << 16);
}

// ---------------- CSR build ----------------
__global__ void hist_kernel(const int* __restrict__ ei, int* __restrict__ deg) {
    int e = blockIdx.x * blockDim.x + threadIdx.x;
    if (e >= E_TOT) return;
    int d = (e < N_EDGES) ? ei[N_EDGES + e] : (e - N_EDGES);
    atomicAdd(&deg[d], 1);
}

// single-block scan over 50000 degrees (replaces 3 kernels)
__global__ __launch_bounds__(1024) void scan_fused(const int* __restrict__ deg,
                                                   int* __restrict__ off,
                                                   int* __restrict__ cur) {
    __shared__ int part[1024];
    const int PER = 49;                 // 1024*49 = 50176 >= 50000
    int t = threadIdx.x;
    int base = t * PER;
    int sum = 0;
#pragma unroll 7
    for (int j = 0; j < PER; ++j) {
        int g = base + j;
        if (g < N_NODES) sum += deg[g];
    }
    part[t] = sum;
    __syncthreads();
    for (int d = 1; d < 1024; d <<= 1) {
        int v = (t >= d) ? part[t - d] : 0;
        __syncthreads();
        part[t] += v;
        __syncthreads();
    }
    int pre = part[t] - sum;            // exclusive prefix of this chunk
    for (int j = 0; j < PER; ++j) {
        int g = base + j;
        if (g < N_NODES) {
            off[g] = pre;
            cur[g] = pre;
            pre += deg[g];
        }
    }
    if (t == 1023) off[N_NODES] = E_TOT;
}

__global__ void scatter_kernel(const int* __restrict__ ei, int* __restrict__ cur,
                               int* __restrict__ ssrc, int* __restrict__ sdst) {
    int e = blockIdx.x * blockDim.x + threadIdx.x;
    if (e >= E_TOT) return;
    int s, d;
    if (e < N_EDGES) { s = ei[e]; d = ei[N_EDGES + e]; }
    else             { s = d = e - N_EDGES; }
    int pos = atomicAdd(&cur[d], 1);
    ssrc[pos] = s;
    sdst[pos] = d;
}

// ---------------- GEMM1 (tiled, 64x256 tile) + alpha epilogue, bf16 h1 out ---
#define FMA4(accv, av, bv)                                                     \
    accv.x = fmaf(av, bv.x, accv.x); accv.y = fmaf(av, bv.y, accv.y);          \
    accv.z = fmaf(av, bv.z, accv.z); accv.w = fmaf(av, bv.w, accv.w);

__global__ __launch_bounds__(256) void gemm1_tiled(
    const float* __restrict__ x, const float* __restrict__ W1,
    const float* __restrict__ att_s, const float* __restrict__ att_d,
    unsigned short* __restrict__ h1b, float* __restrict__ as1, float* __restrict__ ad1) {
    __shared__ float As[M_BLK][IN_CH];   // 32 KB
    int t = threadIdx.x;
    int row0 = blockIdx.x * M_BLK;
#pragma unroll
    for (int i = 0; i < 8; ++i) {
        int f = t + i * 256;
        int r = f >> 5, c4 = (f & 31) * 4;
        int gr = row0 + r; if (gr >= N_NODES) gr = N_NODES - 1;
        *(float4*)&As[r][c4] = *(const float4*)&x[(size_t)gr * IN_CH + c4];
    }
    __syncthreads();
    int col0 = (t & 63) * 4;
    int rbase = (t >> 6) * 16;
    float4 acc[16];
#pragma unroll
    for (int m = 0; m < 16; ++m) acc[m] = make_float4(0.f, 0.f, 0.f, 0.f);

    for (int k = 0; k < IN_CH; k += 4) {
        float4 b0 = *(const float4*)&W1[(k + 0) * 256 + col0];
        float4 b1 = *(const float4*)&W1[(k + 1) * 256 + col0];
        float4 b2 = *(const float4*)&W1[(k + 2) * 256 + col0];
        float4 b3 = *(const float4*)&W1[(k + 3) * 256 + col0];
#pragma unroll
        for (int m = 0; m < 16; ++m) {
            float4 a = *(const float4*)&As[rbase + m][k];
            FMA4(acc[m], a.x, b0);
            FMA4(acc[m], a.y, b1);
            FMA4(acc[m], a.z, b2);
            FMA4(acc[m], a.w, b3);
        }
    }

    float4 s4 = *(const float4*)&att_s[col0];
    float4 d4 = *(const float4*)&att_d[col0];
    int head = col0 >> 5;
#pragma unroll
    for (int m = 0; m < 16; ++m) {
        int gr = row0 + rbase + m;
        if (gr < N_NODES) {
            ushort4 hb;
            hb.x = f2bf(acc[m].x); hb.y = f2bf(acc[m].y);
            hb.z = f2bf(acc[m].z); hb.w = f2bf(acc[m].w);
            *(ushort4*)&h1b[(size_t)gr * 256 + col0] = hb;
            float p = acc[m].x * s4.x + acc[m].y * s4.y + acc[m].z * s4.z + acc[m].w * s4.w;
            float q = acc[m].x * d4.x + acc[m].y * d4.y + acc[m].z * d4.z + acc[m].w * d4.w;
            p += __shfl_xor(p, 1); p += __shfl_xor(p, 2); p += __shfl_xor(p, 4);
            q += __shfl_xor(q, 1); q += __shfl_xor(q, 2); q += __shfl_xor(q, 4);
            if ((t & 7) == 0) {
                as1[gr * HEADS + head] = p;
                ad1[gr * HEADS + head] = q;
            }
        }
    }
}

// ---------------- Edge weights, layer 1: w = exp(lrelu(as[src]+ad[dst])) ----
__global__ __launch_bounds__(256) void wk1_kernel(
    const int* __restrict__ ssrc, const int* __restrict__ sdst,
    const float* __restrict__ as1, const float* __restrict__ ad1,
    float* __restrict__ w1buf) {
    int i = blockIdx.x * 256 + threadIdx.x;
    if (i >= E_TOT) return;
    int s = __builtin_nontemporal_load(&ssrc[i]);
    int d = __builtin_nontemporal_load(&sdst[i]);
    float4 a0 = *(const float4*)&as1[s * 8];
    float4 a1 = *(const float4*)&as1[s * 8 + 4];
    float4 d0 = *(const float4*)&ad1[d * 8];
    float4 d1 = *(const float4*)&ad1[d * 8 + 4];
    float4 w0, w1;
    w0.x = __expf(lrelu(a0.x + d0.x)); w0.y = __expf(lrelu(a0.y + d0.y));
    w0.z = __expf(lrelu(a0.z + d0.z)); w0.w = __expf(lrelu(a0.w + d0.w));
    w1.x = __expf(lrelu(a1.x + d1.x)); w1.y = __expf(lrelu(a1.y + d1.y));
    w1.z = __expf(lrelu(a1.z + d1.z)); w1.w = __expf(lrelu(a1.w + d1.w));
    *(float4*)&w1buf[(size_t)i * 8]     = w0;
    *(float4*)&w1buf[(size_t)i * 8 + 4] = w1;
}

// ---------------- Aggregate layer 1: 1 wave/node, precomputed weights -------
__global__ __launch_bounds__(256) void agg1_kernel(
    const int* __restrict__ off, const int* __restrict__ ssrc,
    const float* __restrict__ w1buf,
    const unsigned short* __restrict__ h1b, const float* __restrict__ b1,
    unsigned short* __restrict__ houtb) {
    int t = threadIdx.x;
    int lane = t & 63;
    int n = blockIdx.x * 4 + (t >> 6);
    int h = lane >> 3;
    int c0 = lane * 4;
    int start = off[n], end = off[n + 1];
    float4 acc0 = make_float4(0.f, 0.f, 0.f, 0.f);
    float4 acc1 = make_float4(0.f, 0.f, 0.f, 0.f);
    float den0 = 0.f, den1 = 0.f;
    int i = start;
    for (; i + 1 < end; i += 2) {
        int s0 = __builtin_nontemporal_load(&ssrc[i]);
        int s1 = __builtin_nontemporal_load(&ssrc[i + 1]);
        float w0 = __builtin_nontemporal_load(&w1buf[(size_t)i * 8 + h]);
        float w1 = __builtin_nontemporal_load(&w1buf[(size_t)(i + 1) * 8 + h]);
        ushort4 u0 = *(const ushort4*)&h1b[(unsigned)s0 * 256 + c0];
        ushort4 u1 = *(const ushort4*)&h1b[(unsigned)s1 * 256 + c0];
        den0 += w0; den1 += w1;
        acc0.x = fmaf(w0, bf2f(u0.x), acc0.x);
        acc0.y = fmaf(w0, bf2f(u0.y), acc0.y);
        acc0.z = fmaf(w0, bf2f(u0.z), acc0.z);
        acc0.w = fmaf(w0, bf2f(u0.w), acc0.w);
        acc1.x = fmaf(w1, bf2f(u1.x), acc1.x);
        acc1.y = fmaf(w1, bf2f(u1.y), acc1.y);
        acc1.z = fmaf(w1, bf2f(u1.z), acc1.z);
        acc1.w = fmaf(w1, bf2f(u1.w), acc1.w);
    }
    if (i < end) {
        int s0 = __builtin_nontemporal_load(&ssrc[i]);
        float w0 = __builtin_nontemporal_load(&w1buf[(size_t)i * 8 + h]);
        ushort4 u0 = *(const ushort4*)&h1b[(unsigned)s0 * 256 + c0];
        den0 += w0;
        acc0.x = fmaf(w0, bf2f(u0.x), acc0.x);
        acc0.y = fmaf(w0, bf2f(u0.y), acc0.y);
        acc0.z = fmaf(w0, bf2f(u0.z), acc0.z);
        acc0.w = fmaf(w0, bf2f(u0.w), acc0.w);
    }
    float r = __builtin_amdgcn_rcpf(den0 + den1);
    float4 bv = *(const float4*)&b1[c0];
    float vx = fmaf(acc0.x + acc1.x, r, bv.x);
    float vy = fmaf(acc0.y + acc1.y, r, bv.y);
    float vz = fmaf(acc0.z + acc1.z, r, bv.z);
    float vw = fmaf(acc0.w + acc1.w, r, bv.w);
    vx = vx > 0.f ? vx : expm1f(vx);
    vy = vy > 0.f ? vy : expm1f(vy);
    vz = vz > 0.f ? vz : expm1f(vz);
    vw = vw > 0.f ? vw : expm1f(vw);
    unsigned long long packed =
        (unsigned long long)f2bf(vx)
      | ((unsigned long long)f2bf(vy) << 16)
      | ((unsigned long long)f2bf(vz) << 32)
      | ((unsigned long long)f2bf(vw) << 48);
    __builtin_nontemporal_store(packed,
        (unsigned long long*)&houtb[(unsigned)n * 256 + c0]);
}

// ---------------- GEMM2 (tiled, 64x64 tile, bf16 in) + alpha epilogue -------
__global__ __launch_bounds__(256) void gemm2_tiled(
    const unsigned short* __restrict__ hinb, const float* __restrict__ W2,
    const float* __restrict__ att_s2, const float* __restrict__ att_d2,
    unsigned short* __restrict__ h2b, float* __restrict__ as2, float* __restrict__ ad2) {
    __shared__ float As[M_BLK][256];   // 64 KB
    int t = threadIdx.x;
    int row0 = blockIdx.x * M_BLK;
#pragma unroll
    for (int i = 0; i < 16; ++i) {
        int f = t + i * 256;
        int r = f >> 6, c4 = (f & 63) * 4;
        int gr = row0 + r; if (gr >= N_NODES) gr = N_NODES - 1;
        ushort4 u = *(const ushort4*)&hinb[(size_t)gr * 256 + c4];
        float4 v = make_float4(bf2f(u.x), bf2f(u.y), bf2f(u.z), bf2f(u.w));
        *(float4*)&As[r][c4] = v;
    }
    __syncthreads();
    int col0 = (t & 31) * 2;
    int rbase = (t >> 5) * 8;
    float2 acc[8];
#pragma unroll
    for (int m = 0; m < 8; ++m) acc[m] = make_float2(0.f, 0.f);

    for (int k = 0; k < 256; k += 4) {
        float2 b0 = *(const float2*)&W2[(k + 0) * 64 + col0];
        float2 b1 = *(const float2*)&W2[(k + 1) * 64 + col0];
        float2 b2 = *(const float2*)&W2[(k + 2) * 64 + col0];
        float2 b3 = *(const float2*)&W2[(k + 3) * 64 + col0];
#pragma unroll
        for (int m = 0; m < 8; ++m) {
            float4 a = *(const float4*)&As[rbase + m][k];
            acc[m].x = fmaf(a.x, b0.x, acc[m].x); acc[m].y = fmaf(a.x, b0.y, acc[m].y);
            acc[m].x = fmaf(a.y, b1.x, acc[m].x); acc[m].y = fmaf(a.y, b1.y, acc[m].y);
            acc[m].x = fmaf(a.z, b2.x, acc[m].x); acc[m].y = fmaf(a.z, b2.y, acc[m].y);
            acc[m].x = fmaf(a.w, b3.x, acc[m].x); acc[m].y = fmaf(a.w, b3.y, acc[m].y);
        }
    }

    float2 s2v = *(const float2*)&att_s2[col0];
    float2 d2v = *(const float2*)&att_d2[col0];
#pragma unroll
    for (int m = 0; m < 8; ++m) {
        int gr = row0 + rbase + m;
        if (gr < N_NODES) {
            ushort2 hb;
            hb.x = f2bf(acc[m].x); hb.y = f2bf(acc[m].y);
            *(ushort2*)&h2b[(size_t)gr * 64 + col0] = hb;
            float p = acc[m].x * s2v.x + acc[m].y * s2v.y;
            float q = acc[m].x * d2v.x + acc[m].y * d2v.y;
            p += __shfl_xor(p, 1);  q += __shfl_xor(q, 1);
            p += __shfl_xor(p, 2);  q += __shfl_xor(q, 2);
            p += __shfl_xor(p, 4);  q += __shfl_xor(q, 4);
            p += __shfl_xor(p, 8);  q += __shfl_xor(q, 8);
            p += __shfl_xor(p, 16); q += __shfl_xor(q, 16);
            if ((t & 31) == 0) { as2[gr] = p; ad2[gr] = q; }
        }
    }
}

// ---------------- Edge weights, layer 2 --------------------------------------
__global__ __launch_bounds__(256) void wk2_kernel(
    const int* __restrict__ ssrc, const int* __restrict__ sdst,
    const float* __restrict__ as2, const float* __restrict__ ad2,
    float* __restrict__ w2buf) {
    int i = blockIdx.x * 256 + threadIdx.x;
    if (i >= E_TOT) return;
    int s = __builtin_nontemporal_load(&ssrc[i]);
    int d = __builtin_nontemporal_load(&sdst[i]);
    w2buf[i] = __expf(lrelu(as2[s] + ad2[d]));
}

// ---------------- Aggregate layer 2: 1 wave/node, precomputed weights -------
__global__ __launch_bounds__(256) void agg2_kernel(
    const int* __restrict__ off, const int* __restrict__ ssrc,
    const float* __restrict__ w2buf,
    const unsigned short* __restrict__ h2b, const float* __restrict__ b2,
    float* __restrict__ out) {
    int t = threadIdx.x;
    int lane = t & 63;
    int n = blockIdx.x * 4 + (t >> 6);
    int start = off[n], end = off[n + 1];
    float acc0 = 0.f, den0 = 0.f, acc1 = 0.f, den1 = 0.f;
    int i = start;
    for (; i + 1 < end; i += 2) {
        int s0 = __builtin_nontemporal_load(&ssrc[i]);
        int s1 = __builtin_nontemporal_load(&ssrc[i + 1]);
        float w0 = __builtin_nontemporal_load(&w2buf[i]);
        float w1 = __builtin_nontemporal_load(&w2buf[i + 1]);
        float v0 = bf2f(h2b[(unsigned)s0 * 64 + lane]);
        float v1 = bf2f(h2b[(unsigned)s1 * 64 + lane]);
        den0 += w0; den1 += w1;
        acc0 = fmaf(w0, v0, acc0);
        acc1 = fmaf(w1, v1, acc1);
    }
    if (i < end) {
        int s0 = __builtin_nontemporal_load(&ssrc[i]);
        float w0 = __builtin_nontemporal_load(&w2buf[i]);
        den0 += w0;
        acc0 = fmaf(w0, bf2f(h2b[(unsigned)s0 * 64 + lane]), acc0);
    }
    float r = __builtin_amdgcn_rcpf(den0 + den1);
    out[(unsigned)n * 64 + lane] = fmaf(acc0 + acc1, r, b2[lane]);
}

extern "C" void kernel_launch(void* const* d_in, const int* in_sizes, int n_in,
                              void* d_out, int out_size, void* d_ws, size_t ws_size,
                              hipStream_t stream) {
    const float* x    = (const float*)d_in[0];
    const int*   ei   = (const int*)d_in[1];
    const float* W1   = (const float*)d_in[2];
    const float* ats1 = (const float*)d_in[3];
    const float* atd1 = (const float*)d_in[4];
    const float* b1   = (const float*)d_in[5];
    const float* W2   = (const float*)d_in[6];
    const float* ats2 = (const float*)d_in[7];
    const float* atd2 = (const float*)d_in[8];
    const float* b2   = (const float*)d_in[9];
    float* out = (float*)d_out;

    char* ws = (char*)d_ws;
    size_t o = 0;
    auto alloc = [&](size_t bytes) { size_t r = o; o = (o + bytes + 255) & ~255UL; return r; };
    unsigned short* h1b   = (unsigned short*)(ws + alloc((size_t)N_NODES * 256 * 2));
    unsigned short* h2inb = (unsigned short*)(ws + alloc((size_t)N_NODES * 256 * 2));
    unsigned short* h2b   = (unsigned short*)(ws + alloc((size_t)N_NODES * 64 * 2));
    float* as1  = (float*)(ws + alloc((size_t)N_NODES * HEADS * 4));
    float* ad1  = (float*)(ws + alloc((size_t)N_NODES * HEADS * 4));
    float* as2  = (float*)(ws + alloc((size_t)N_NODES * 4));
    float* ad2  = (float*)(ws + alloc((size_t)N_NODES * 4));
    int*   deg  = (int*)(ws + alloc((size_t)N_NODES * 4));
    int*   off  = (int*)(ws + alloc((size_t)(N_NODES + 1) * 4));
    int*   cur  = (int*)(ws + alloc((size_t)N_NODES * 4));
    int*   ssrc = (int*)(ws + alloc((size_t)E_TOT * 4));
    int*   sdst = (int*)(ws + alloc((size_t)E_TOT * 4));
    float* w1buf = (float*)(ws + alloc((size_t)E_TOT * HEADS * 4));
    float* w2buf = (float*)(ws + alloc((size_t)E_TOT * 4));

    (void)hipMemsetAsync(deg, 0, (size_t)N_NODES * 4, stream);
    int eblk = (E_TOT + 255) / 256;
    hist_kernel<<<eblk, 256, 0, stream>>>(ei, deg);
    scan_fused<<<1, 1024, 0, stream>>>(deg, off, cur);
    scatter_kernel<<<eblk, 256, 0, stream>>>(ei, cur, ssrc, sdst);

    gemm1_tiled<<<GBLK, 256, 0, stream>>>(x, W1, ats1, atd1, h1b, as1, ad1);
    wk1_kernel<<<eblk, 256, 0, stream>>>(ssrc, sdst, as1, ad1, w1buf);
    agg1_kernel<<<ABLK, 256, 0, stream>>>(off, ssrc, w1buf, h1b, b1, h2inb);

    gemm2_tiled<<<GBLK, 256, 0, stream>>>(h2inb, W2, ats2, atd2, h2b, as2, ad2);
    wk2_kernel<<<eblk, 256, 0, stream>>>(ssrc, sdst, as2, ad2, w2buf);
    agg2_kernel<<<ABLK, 256, 0, stream>>>(off, ssrc, w2buf, h2b, b2, out);
}

// Round 8
// 374.464 us; speedup vs baseline: 1.3114x; 1.3114x over previous
//
#include <hip/hip_runtime.h>
#include <hip/hip_bf16.h>
#include <math.h>

#define N_NODES 50000
#define N_EDGES 800000
#define E_TOT   (N_EDGES + N_NODES)   // 850000 (with self-loops)
#define IN_CH 128
#define HID 32
#define HEADS 8
#define OUT_CH 64
#define NEG_SLOPE 0.2f
#define NBLK 196                      // ceil(50000/256)
#define M_BLK 64
#define GBLK 782                      // ceil(50000/64)
#define ABLK 12500                    // 50000/4 nodes per 256-thread block

__device__ __forceinline__ float lrelu(float x) { return x > 0.f ? x : NEG_SLOPE * x; }

__device__ __forceinline__ unsigned short f2bf(float f) {
    unsigned int u = __float_as_uint(f);
    unsigned int r = (u + 0x7FFFu + ((u >> 16) & 1u)) >> 16;   // round-nearest-even
    return (unsigned short)r;
}
__device__ __forceinline__ float bf2f(unsigned short u) {
    return __uint_as_float(((unsigned int)u) << 16);
}

// ---------------- CSR build ----------------
__global__ void hist_kernel(const int* __restrict__ ei, int* __restrict__ deg) {
    int e = blockIdx.x * blockDim.x + threadIdx.x;
    if (e >= E_TOT) return;
    int d = (e < N_EDGES) ? ei[N_EDGES + e] : (e - N_EDGES);
    atomicAdd(&deg[d], 1);
}

__global__ void scan1_kernel(const int* __restrict__ deg, int* __restrict__ off,
                             int* __restrict__ bsum) {
    __shared__ int s[256];
    int b = blockIdx.x, t = threadIdx.x, g = b * 256 + t;
    int v = (g < N_NODES) ? deg[g] : 0;
    s[t] = v;
    __syncthreads();
    for (int d = 1; d < 256; d <<= 1) {
        int o = (t >= d) ? s[t - d] : 0;
        __syncthreads();
        s[t] += o;
        __syncthreads();
    }
    if (g < N_NODES) off[g] = s[t] - v;      // exclusive, pre-block-offset
    if (t == 255) bsum[b] = s[t];
}

__global__ void scan2_kernel(int* __restrict__ bsum, int nb) {
    __shared__ int s[256];
    int t = threadIdx.x;
    int v = (t < nb) ? bsum[t] : 0;
    s[t] = v;
    __syncthreads();
    for (int d = 1; d < 256; d <<= 1) {
        int o = (t >= d) ? s[t - d] : 0;
        __syncthreads();
        s[t] += o;
        __syncthreads();
    }
    if (t < nb) bsum[t] = s[t] - v;          // exclusive block offsets
}

__global__ void scan3_kernel(int* __restrict__ off, const int* __restrict__ bsum,
                             int* __restrict__ cur) {
    int b = blockIdx.x, t = threadIdx.x, g = b * 256 + t;
    if (g < N_NODES) {
        int v = off[g] + bsum[b];
        off[g] = v;
        cur[g] = v;
    }
    if (g == 0) off[N_NODES] = E_TOT;
}

__global__ void scatter_kernel(const int* __restrict__ ei, int* __restrict__ cur,
                               int* __restrict__ ssrc, int* __restrict__ sdst) {
    int e = blockIdx.x * blockDim.x + threadIdx.x;
    if (e >= E_TOT) return;
    int s, d;
    if (e < N_EDGES) { s = ei[e]; d = ei[N_EDGES + e]; }
    else             { s = d = e - N_EDGES; }
    int pos = atomicAdd(&cur[d], 1);
    ssrc[pos] = s;
    sdst[pos] = d;
}

// ---------------- GEMM1 (tiled, 64x256 tile) + alpha epilogue, bf16 h1 out ---
#define FMA4(accv, av, bv)                                                     \
    accv.x = fmaf(av, bv.x, accv.x); accv.y = fmaf(av, bv.y, accv.y);          \
    accv.z = fmaf(av, bv.z, accv.z); accv.w = fmaf(av, bv.w, accv.w);

__global__ __launch_bounds__(256) void gemm1_tiled(
    const float* __restrict__ x, const float* __restrict__ W1,
    const float* __restrict__ att_s, const float* __restrict__ att_d,
    unsigned short* __restrict__ h1b, float* __restrict__ as1, float* __restrict__ ad1) {
    __shared__ float As[M_BLK][IN_CH];   // 32 KB
    int t = threadIdx.x;
    int row0 = blockIdx.x * M_BLK;
#pragma unroll
    for (int i = 0; i < 8; ++i) {
        int f = t + i * 256;
        int r = f >> 5, c4 = (f & 31) * 4;
        int gr = row0 + r; if (gr >= N_NODES) gr = N_NODES - 1;
        *(float4*)&As[r][c4] = *(const float4*)&x[(size_t)gr * IN_CH + c4];
    }
    __syncthreads();
    int col0 = (t & 63) * 4;
    int rbase = (t >> 6) * 16;
    float4 acc[16];
#pragma unroll
    for (int m = 0; m < 16; ++m) acc[m] = make_float4(0.f, 0.f, 0.f, 0.f);

    for (int k = 0; k < IN_CH; k += 4) {
        float4 b0 = *(const float4*)&W1[(k + 0) * 256 + col0];
        float4 b1 = *(const float4*)&W1[(k + 1) * 256 + col0];
        float4 b2 = *(const float4*)&W1[(k + 2) * 256 + col0];
        float4 b3 = *(const float4*)&W1[(k + 3) * 256 + col0];
#pragma unroll
        for (int m = 0; m < 16; ++m) {
            float4 a = *(const float4*)&As[rbase + m][k];
            FMA4(acc[m], a.x, b0);
            FMA4(acc[m], a.y, b1);
            FMA4(acc[m], a.z, b2);
            FMA4(acc[m], a.w, b3);
        }
    }

    float4 s4 = *(const float4*)&att_s[col0];
    float4 d4 = *(const float4*)&att_d[col0];
    int head = col0 >> 5;
#pragma unroll
    for (int m = 0; m < 16; ++m) {
        int gr = row0 + rbase + m;
        if (gr < N_NODES) {
            ushort4 hb;
            hb.x = f2bf(acc[m].x); hb.y = f2bf(acc[m].y);
            hb.z = f2bf(acc[m].z); hb.w = f2bf(acc[m].w);
            *(ushort4*)&h1b[(size_t)gr * 256 + col0] = hb;
            float p = acc[m].x * s4.x + acc[m].y * s4.y + acc[m].z * s4.z + acc[m].w * s4.w;
            float q = acc[m].x * d4.x + acc[m].y * d4.y + acc[m].z * d4.z + acc[m].w * d4.w;
            p += __shfl_xor(p, 1); p += __shfl_xor(p, 2); p += __shfl_xor(p, 4);
            q += __shfl_xor(q, 1); q += __shfl_xor(q, 2); q += __shfl_xor(q, 4);
            if ((t & 7) == 0) {
                as1[gr * HEADS + head] = p;
                ad1[gr * HEADS + head] = q;
            }
        }
    }
}

// ---------------- Edge weights, layer 1: w = exp(lrelu(as[src]+ad[dst])) ----
__global__ __launch_bounds__(256) void wk1_kernel(
    const int* __restrict__ ssrc, const int* __restrict__ sdst,
    const float* __restrict__ as1, const float* __restrict__ ad1,
    float* __restrict__ w1buf) {
    int i = blockIdx.x * 256 + threadIdx.x;
    if (i >= E_TOT) return;
    int s = __builtin_nontemporal_load(&ssrc[i]);
    int d = __builtin_nontemporal_load(&sdst[i]);
    float4 a0 = *(const float4*)&as1[s * 8];
    float4 a1 = *(const float4*)&as1[s * 8 + 4];
    float4 d0 = *(const float4*)&ad1[d * 8];
    float4 d1 = *(const float4*)&ad1[d * 8 + 4];
    float4 w0, w1;
    w0.x = __expf(lrelu(a0.x + d0.x)); w0.y = __expf(lrelu(a0.y + d0.y));
    w0.z = __expf(lrelu(a0.z + d0.z)); w0.w = __expf(lrelu(a0.w + d0.w));
    w1.x = __expf(lrelu(a1.x + d1.x)); w1.y = __expf(lrelu(a1.y + d1.y));
    w1.z = __expf(lrelu(a1.z + d1.z)); w1.w = __expf(lrelu(a1.w + d1.w));
    *(float4*)&w1buf[(size_t)i * 8]     = w0;
    *(float4*)&w1buf[(size_t)i * 8 + 4] = w1;
}

// ---------------- Aggregate layer 1: 1 wave/node, precomputed weights -------
__global__ __launch_bounds__(256) void agg1_kernel(
    const int* __restrict__ off, const int* __restrict__ ssrc,
    const float* __restrict__ w1buf,
    const unsigned short* __restrict__ h1b, const float* __restrict__ b1,
    unsigned short* __restrict__ houtb) {
    int t = threadIdx.x;
    int lane = t & 63;
    int n = blockIdx.x * 4 + (t >> 6);
    int h = lane >> 3;
    int c0 = lane * 4;
    int start = off[n], end = off[n + 1];
    float4 acc0 = make_float4(0.f, 0.f, 0.f, 0.f);
    float4 acc1 = make_float4(0.f, 0.f, 0.f, 0.f);
    float den0 = 0.f, den1 = 0.f;
    int i = start;
    for (; i + 1 < end; i += 2) {
        int s0 = __builtin_nontemporal_load(&ssrc[i]);
        int s1 = __builtin_nontemporal_load(&ssrc[i + 1]);
        float w0 = __builtin_nontemporal_load(&w1buf[(size_t)i * 8 + h]);
        float w1 = __builtin_nontemporal_load(&w1buf[(size_t)(i + 1) * 8 + h]);
        ushort4 u0 = *(const ushort4*)&h1b[(unsigned)s0 * 256 + c0];
        ushort4 u1 = *(const ushort4*)&h1b[(unsigned)s1 * 256 + c0];
        den0 += w0; den1 += w1;
        acc0.x = fmaf(w0, bf2f(u0.x), acc0.x);
        acc0.y = fmaf(w0, bf2f(u0.y), acc0.y);
        acc0.z = fmaf(w0, bf2f(u0.z), acc0.z);
        acc0.w = fmaf(w0, bf2f(u0.w), acc0.w);
        acc1.x = fmaf(w1, bf2f(u1.x), acc1.x);
        acc1.y = fmaf(w1, bf2f(u1.y), acc1.y);
        acc1.z = fmaf(w1, bf2f(u1.z), acc1.z);
        acc1.w = fmaf(w1, bf2f(u1.w), acc1.w);
    }
    if (i < end) {
        int s0 = __builtin_nontemporal_load(&ssrc[i]);
        float w0 = __builtin_nontemporal_load(&w1buf[(size_t)i * 8 + h]);
        ushort4 u0 = *(const ushort4*)&h1b[(unsigned)s0 * 256 + c0];
        den0 += w0;
        acc0.x = fmaf(w0, bf2f(u0.x), acc0.x);
        acc0.y = fmaf(w0, bf2f(u0.y), acc0.y);
        acc0.z = fmaf(w0, bf2f(u0.z), acc0.z);
        acc0.w = fmaf(w0, bf2f(u0.w), acc0.w);
    }
    float r = __builtin_amdgcn_rcpf(den0 + den1);
    float4 bv = *(const float4*)&b1[c0];
    float vx = fmaf(acc0.x + acc1.x, r, bv.x);
    float vy = fmaf(acc0.y + acc1.y, r, bv.y);
    float vz = fmaf(acc0.z + acc1.z, r, bv.z);
    float vw = fmaf(acc0.w + acc1.w, r, bv.w);
    vx = vx > 0.f ? vx : expm1f(vx);
    vy = vy > 0.f ? vy : expm1f(vy);
    vz = vz > 0.f ? vz : expm1f(vz);
    vw = vw > 0.f ? vw : expm1f(vw);
    unsigned long long packed =
        (unsigned long long)f2bf(vx)
      | ((unsigned long long)f2bf(vy) << 16)
      | ((unsigned long long)f2bf(vz) << 32)
      | ((unsigned long long)f2bf(vw) << 48);
    __builtin_nontemporal_store(packed,
        (unsigned long long*)&houtb[(unsigned)n * 256 + c0]);
}

// ---------------- GEMM2 (tiled, 64x64 tile, bf16 in) + alpha epilogue -------
__global__ __launch_bounds__(256) void gemm2_tiled(
    const unsigned short* __restrict__ hinb, const float* __restrict__ W2,
    const float* __restrict__ att_s2, const float* __restrict__ att_d2,
    unsigned short* __restrict__ h2b, float* __restrict__ as2, float* __restrict__ ad2) {
    __shared__ float As[M_BLK][256];   // 64 KB
    int t = threadIdx.x;
    int row0 = blockIdx.x * M_BLK;
#pragma unroll
    for (int i = 0; i < 16; ++i) {
        int f = t + i * 256;
        int r = f >> 6, c4 = (f & 63) * 4;
        int gr = row0 + r; if (gr >= N_NODES) gr = N_NODES - 1;
        ushort4 u = *(const ushort4*)&hinb[(size_t)gr * 256 + c4];
        float4 v = make_float4(bf2f(u.x), bf2f(u.y), bf2f(u.z), bf2f(u.w));
        *(float4*)&As[r][c4] = v;
    }
    __syncthreads();
    int col0 = (t & 31) * 2;
    int rbase = (t >> 5) * 8;
    float2 acc[8];
#pragma unroll
    for (int m = 0; m < 8; ++m) acc[m] = make_float2(0.f, 0.f);

    for (int k = 0; k < 256; k += 4) {
        float2 b0 = *(const float2*)&W2[(k + 0) * 64 + col0];
        float2 b1 = *(const float2*)&W2[(k + 1) * 64 + col0];
        float2 b2 = *(const float2*)&W2[(k + 2) * 64 + col0];
        float2 b3 = *(const float2*)&W2[(k + 3) * 64 + col0];
#pragma unroll
        for (int m = 0; m < 8; ++m) {
            float4 a = *(const float4*)&As[rbase + m][k];
            acc[m].x = fmaf(a.x, b0.x, acc[m].x); acc[m].y = fmaf(a.x, b0.y, acc[m].y);
            acc[m].x = fmaf(a.y, b1.x, acc[m].x); acc[m].y = fmaf(a.y, b1.y, acc[m].y);
            acc[m].x = fmaf(a.z, b2.x, acc[m].x); acc[m].y = fmaf(a.z, b2.y, acc[m].y);
            acc[m].x = fmaf(a.w, b3.x, acc[m].x); acc[m].y = fmaf(a.w, b3.y, acc[m].y);
        }
    }

    float2 s2v = *(const float2*)&att_s2[col0];
    float2 d2v = *(const float2*)&att_d2[col0];
#pragma unroll
    for (int m = 0; m < 8; ++m) {
        int gr = row0 + rbase + m;
        if (gr < N_NODES) {
            ushort2 hb;
            hb.x = f2bf(acc[m].x); hb.y = f2bf(acc[m].y);
            *(ushort2*)&h2b[(size_t)gr * 64 + col0] = hb;
            float p = acc[m].x * s2v.x + acc[m].y * s2v.y;
            float q = acc[m].x * d2v.x + acc[m].y * d2v.y;
            p += __shfl_xor(p, 1);  q += __shfl_xor(q, 1);
            p += __shfl_xor(p, 2);  q += __shfl_xor(q, 2);
            p += __shfl_xor(p, 4);  q += __shfl_xor(q, 4);
            p += __shfl_xor(p, 8);  q += __shfl_xor(q, 8);
            p += __shfl_xor(p, 16); q += __shfl_xor(q, 16);
            if ((t & 31) == 0) { as2[gr] = p; ad2[gr] = q; }
        }
    }
}

// ---------------- Edge weights, layer 2 --------------------------------------
__global__ __launch_bounds__(256) void wk2_kernel(
    const int* __restrict__ ssrc, const int* __restrict__ sdst,
    const float* __restrict__ as2, const float* __restrict__ ad2,
    float* __restrict__ w2buf) {
    int i = blockIdx.x * 256 + threadIdx.x;
    if (i >= E_TOT) return;
    int s = __builtin_nontemporal_load(&ssrc[i]);
    int d = __builtin_nontemporal_load(&sdst[i]);
    w2buf[i] = __expf(lrelu(as2[s] + ad2[d]));
}

// ---------------- Aggregate layer 2: 1 wave/node, precomputed weights -------
__global__ __launch_bounds__(256) void agg2_kernel(
    const int* __restrict__ off, const int* __restrict__ ssrc,
    const float* __restrict__ w2buf,
    const unsigned short* __restrict__ h2b, const float* __restrict__ b2,
    float* __restrict__ out) {
    int t = threadIdx.x;
    int lane = t & 63;
    int n = blockIdx.x * 4 + (t >> 6);
    int start = off[n], end = off[n + 1];
    float acc0 = 0.f, den0 = 0.f, acc1 = 0.f, den1 = 0.f;
    int i = start;
    for (; i + 1 < end; i += 2) {
        int s0 = __builtin_nontemporal_load(&ssrc[i]);
        int s1 = __builtin_nontemporal_load(&ssrc[i + 1]);
        float w0 = __builtin_nontemporal_load(&w2buf[i]);
        float w1 = __builtin_nontemporal_load(&w2buf[i + 1]);
        float v0 = bf2f(h2b[(unsigned)s0 * 64 + lane]);
        float v1 = bf2f(h2b[(unsigned)s1 * 64 + lane]);
        den0 += w0; den1 += w1;
        acc0 = fmaf(w0, v0, acc0);
        acc1 = fmaf(w1, v1, acc1);
    }
    if (i < end) {
        int s0 = __builtin_nontemporal_load(&ssrc[i]);
        float w0 = __builtin_nontemporal_load(&w2buf[i]);
        den0 += w0;
        acc0 = fmaf(w0, bf2f(h2b[(unsigned)s0 * 64 + lane]), acc0);
    }
    float r = __builtin_amdgcn_rcpf(den0 + den1);
    out[(unsigned)n * 64 + lane] = fmaf(acc0 + acc1, r, b2[lane]);
}

extern "C" void kernel_launch(void* const* d_in, const int* in_sizes, int n_in,
                              void* d_out, int out_size, void* d_ws, size_t ws_size,
                              hipStream_t stream) {
    const float* x    = (const float*)d_in[0];
    const int*   ei   = (const int*)d_in[1];
    const float* W1   = (const float*)d_in[2];
    const float* ats1 = (const float*)d_in[3];
    const float* atd1 = (const float*)d_in[4];
    const float* b1   = (const float*)d_in[5];
    const float* W2   = (const float*)d_in[6];
    const float* ats2 = (const float*)d_in[7];
    const float* atd2 = (const float*)d_in[8];
    const float* b2   = (const float*)d_in[9];
    float* out = (float*)d_out;

    char* ws = (char*)d_ws;
    size_t o = 0;
    auto alloc = [&](size_t bytes) { size_t r = o; o = (o + bytes + 255) & ~255UL; return r; };
    unsigned short* h1b   = (unsigned short*)(ws + alloc((size_t)N_NODES * 256 * 2));
    unsigned short* h2inb = (unsigned short*)(ws + alloc((size_t)N_NODES * 256 * 2));
    unsigned short* h2b   = (unsigned short*)(ws + alloc((size_t)N_NODES * 64 * 2));
    float* as1  = (float*)(ws + alloc((size_t)N_NODES * HEADS * 4));
    float* ad1  = (float*)(ws + alloc((size_t)N_NODES * HEADS * 4));
    float* as2  = (float*)(ws + alloc((size_t)N_NODES * 4));
    float* ad2  = (float*)(ws + alloc((size_t)N_NODES * 4));
    int*   deg  = (int*)(ws + alloc((size_t)N_NODES * 4));
    int*   off  = (int*)(ws + alloc((size_t)(N_NODES + 1) * 4));
    int*   cur  = (int*)(ws + alloc((size_t)N_NODES * 4));
    int*   bsum = (int*)(ws + alloc(256 * 4));
    int*   ssrc = (int*)(ws + alloc((size_t)E_TOT * 4));
    int*   sdst = (int*)(ws + alloc((size_t)E_TOT * 4));
    float* w1buf = (float*)(ws + alloc((size_t)E_TOT * HEADS * 4));
    float* w2buf = (float*)(ws + alloc((size_t)E_TOT * 4));

    (void)hipMemsetAsync(deg, 0, (size_t)N_NODES * 4, stream);
    int eblk = (E_TOT + 255) / 256;
    hist_kernel<<<eblk, 256, 0, stream>>>(ei, deg);
    scan1_kernel<<<NBLK, 256, 0, stream>>>(deg, off, bsum);
    scan2_kernel<<<1, 256, 0, stream>>>(bsum, NBLK);
    scan3_kernel<<<NBLK, 256, 0, stream>>>(off, bsum, cur);
    scatter_kernel<<<eblk, 256, 0, stream>>>(ei, cur, ssrc, sdst);

    gemm1_tiled<<<GBLK, 256, 0, stream>>>(x, W1, ats1, atd1, h1b, as1, ad1);
    wk1_kernel<<<eblk, 256, 0, stream>>>(ssrc, sdst, as1, ad1, w1buf);
    agg1_kernel<<<ABLK, 256, 0, stream>>>(off, ssrc, w1buf, h1b, b1, h2inb);

    gemm2_tiled<<<GBLK, 256, 0, stream>>>(h2inb, W2, ats2, atd2, h2b, as2, ad2);
    wk2_kernel<<<eblk, 256, 0, stream>>>(ssrc, sdst, as2, ad2, w2buf);
    agg2_kernel<<<ABLK, 256, 0, stream>>>(off, ssrc, w2buf, h2b, b2, out);
}